// Round 2
// baseline (325.483 us; speedup 1.0000x reference)
//
#include <hip/hip_runtime.h>
#include <cstdint>

#define BH 48
#define SEQ 4096
#define DIM 64
#define NCHUNK 8
#define CHUNK 512
#define PAD 68

static constexpr float INV_SCALE = 0.35355339059327379f; // 1/sqrt(sqrt(64))

// workspace float offsets (total 2,580,576 floats ~10.3 MB, same as round 1)
#define OFF_QL   0u        // 48*4096  (dead after k2 -> reused as W)
#define OFF_KL   196608u   // 48*4096  (dead after k2 -> reused as P)
#define OFF_QLT  393216u   // 48*4096  QL^T [d][m]
#define OFF_KLT  589824u   // 48*4096  KL^T [d][m]
#define OFF_K2   786432u   // 48*4096
#define OFF_MNUM 983040u   // 48*8*4096
#define OFF_MDEN 2555904u  // 48*8*64
#define OFF_CMAX 2580480u  // 48
#define OFF_RMAX 2580528u  // 48
#define OFF_W    OFF_QL
#define OFF_P    OFF_KL

__device__ __forceinline__ float4 ld4(const float* p){ return *reinterpret_cast<const float4*>(p); }
__device__ __forceinline__ void st4(float* p, float4 v){ *reinterpret_cast<float4*>(p) = v; }

// nn-form: C[4][4] += A[i0..i0+3][k] * B[k][j0..j0+3], k=0..63 (row-major LDS, PAD=68)
__device__ __forceinline__ void mm_nn(float c[4][4], const float (*A)[PAD], const float (*B)[PAD], int i0, int j0){
  #pragma unroll 4
  for(int k=0;k<64;k+=4){
    float4 a4[4];
    #pragma unroll
    for(int r=0;r<4;r++) a4[r] = ld4(&A[i0+r][k]);
    #pragma unroll
    for(int kk=0;kk<4;kk++){
      float4 bv = ld4(&B[k+kk][j0]);
      #pragma unroll
      for(int r=0;r<4;r++){
        float a = ((const float*)&a4[r])[kk];
        c[r][0] += a*bv.x; c[r][1] += a*bv.y; c[r][2] += a*bv.z; c[r][3] += a*bv.w;
      }
    }
  }
}

// tn-form: C[4][4] += sum_k A[k][i0..i0+3] * B[k][j0..j0+3]  (A^T @ B, no transpose needed)
__device__ __forceinline__ void mm_tn(float c[4][4], const float (*A)[PAD], const float (*B)[PAD], int i0, int j0){
  #pragma unroll 8
  for(int k=0;k<64;k++){
    float4 av = ld4(&A[k][i0]);
    float4 bv = ld4(&B[k][j0]);
    c[0][0]+=av.x*bv.x; c[0][1]+=av.x*bv.y; c[0][2]+=av.x*bv.z; c[0][3]+=av.x*bv.w;
    c[1][0]+=av.y*bv.x; c[1][1]+=av.y*bv.y; c[1][2]+=av.y*bv.z; c[1][3]+=av.y*bv.w;
    c[2][0]+=av.z*bv.x; c[2][1]+=av.z*bv.y; c[2][2]+=av.z*bv.z; c[2][3]+=av.z*bv.w;
    c[3][0]+=av.w*bv.x; c[3][1]+=av.w*bv.y; c[3][2]+=av.w*bv.z; c[3][3]+=av.w*bv.w;
  }
}

// C[4][4] += A * (dg*I - B)   (Newton-Schulz steps)
__device__ __forceinline__ void mm_nn_diag(float c[4][4], const float (*A)[PAD], const float (*B)[PAD], int i0, int j0, float dg){
  #pragma unroll 4
  for(int k=0;k<64;k+=4){
    float4 a4[4];
    #pragma unroll
    for(int r=0;r<4;r++) a4[r] = ld4(&A[i0+r][k]);
    #pragma unroll
    for(int kk=0;kk<4;kk++){
      float4 bv = ld4(&B[k+kk][j0]);
      float b0=-bv.x, b1=-bv.y, b2=-bv.z, b3=-bv.w;
      int dd = k+kk-j0;
      if(dd==0) b0+=dg; else if(dd==1) b1+=dg; else if(dd==2) b2+=dg; else if(dd==3) b3+=dg;
      #pragma unroll
      for(int r=0;r<4;r++){
        float a = ((const float*)&a4[r])[kk];
        c[r][0]+=a*b0; c[r][1]+=a*b1; c[r][2]+=a*b2; c[r][3]+=a*b3;
      }
    }
  }
}

// ---------------- 1. landmark pooling (reads Q,K once; writes scaled QL,KL) ----------------
__global__ __launch_bounds__(256) void pool_kernel(const float* __restrict__ Qg, const float* __restrict__ Kg, float* __restrict__ ws){
  int bx = blockIdx.x;              // 48 heads * 2 tensors * 16 landmark-groups = 1536
  int head = bx >> 5;
  int rest = bx & 31;
  int tensor = rest >> 4;           // 0:Q 1:K
  int l0 = (rest & 15) * 4;
  int t = threadIdx.x;
  int ll = t >> 6;
  int lane = t & 63;
  int d4 = (lane & 15) * 4;
  int rq = lane >> 4;
  const float* src = tensor ? Kg : Qg;
  float* dst = ws + (tensor ? OFF_KL : OFF_QL);
  int l = l0 + ll;
  const float* base = src + ((size_t)head*SEQ + (size_t)l*DIM)*DIM + d4; // l*SEG*DIM, SEG==DIM==64
  float sx=0.f, sy=0.f, sz=0.f, sw=0.f;
  #pragma unroll 4
  for(int r=rq; r<64; r+=4){
    float4 v = ld4(base + (size_t)r*DIM);
    sx+=v.x; sy+=v.y; sz+=v.z; sw+=v.w;
  }
  sx += __shfl_xor(sx,16); sy += __shfl_xor(sy,16); sz += __shfl_xor(sz,16); sw += __shfl_xor(sw,16);
  sx += __shfl_xor(sx,32); sy += __shfl_xor(sy,32); sz += __shfl_xor(sz,32); sw += __shfl_xor(sw,32);
  if(rq==0){
    const float sc = INV_SCALE / 64.0f;
    float4 o; o.x=sx*sc; o.y=sy*sc; o.z=sz*sc; o.w=sw*sc;
    st4(dst + ((size_t)head*64 + l)*DIM + d4, o);
  }
}

// ---------------- 2. kernel_2 softmax + L1 norms + emit QL^T, KL^T ----------------
__global__ __launch_bounds__(256) void k2_kernel(float* __restrict__ ws){
  __shared__ float sQ[64][65];
  __shared__ float sK[64][65];
  __shared__ float sE[64][65];
  __shared__ float red[128];
  int h = blockIdx.x, t = threadIdx.x;
  const float* QL = ws + OFF_QL + (size_t)h*4096;
  const float* KL = ws + OFF_KL + (size_t)h*4096;
  for(int i=t;i<4096;i+=256){ sQ[i>>6][i&63]=QL[i]; sK[i>>6][i&63]=KL[i]; }
  __syncthreads();
  // transposed copies for later kernels (conflict-free: stride-65 column reads)
  for(int i=t;i<4096;i+=256){
    int d=i>>6, m=i&63;
    ws[OFF_QLT + (size_t)h*4096 + i] = sQ[m][d];
    ws[OFF_KLT + (size_t)h*4096 + i] = sK[m][d];
  }
  int i = t>>2, q = t&3;
  float lg[16];
  #pragma unroll
  for(int jj=0;jj<16;jj++){
    int j = q*16+jj;
    float s=0.f;
    for(int d=0;d<64;d++) s += sQ[i][d]*sK[j][d];
    lg[jj]=s;
  }
  float mx = lg[0];
  #pragma unroll
  for(int jj=1;jj<16;jj++) mx = fmaxf(mx,lg[jj]);
  mx = fmaxf(mx, __shfl_xor(mx,1));
  mx = fmaxf(mx, __shfl_xor(mx,2));
  float sum=0.f;
  #pragma unroll
  for(int jj=0;jj<16;jj++){ lg[jj]=__expf(lg[jj]-mx); sum+=lg[jj]; }
  sum += __shfl_xor(sum,1);
  sum += __shfl_xor(sum,2);
  float inv = 1.0f/sum;
  #pragma unroll
  for(int jj=0;jj<16;jj++) sE[i][q*16+jj] = lg[jj]*inv;
  __syncthreads();
  float* K2 = ws + OFF_K2 + (size_t)h*4096;
  for(int idx=t; idx<4096; idx+=256) K2[idx] = sE[idx>>6][idx&63];
  if(t<64){
    float cs=0.f, rs=0.f;
    for(int r=0;r<64;r++){ cs += sE[r][t]; rs += sE[t][r]; }
    red[t]=cs; red[64+t]=rs;
  }
  __syncthreads();
  if(t==0){
    float cm=0.f, rm=0.f;
    for(int j=0;j<64;j++){ cm=fmaxf(cm,red[j]); rm=fmaxf(rm,red[64+j]); }
    ws[OFF_CMAX+h]=cm; ws[OFF_RMAX+h]=rm;
  }
}

// ---------------- 3. fused: Newton-Schulz (bid%9==0) || kernel_3@V partials ----------------
__global__ __launch_bounds__(256) void fused_kernel(const float* __restrict__ Kg, const float* __restrict__ Vg, float* __restrict__ ws){
  __shared__ float buf[4][64][PAD];
  __shared__ float dred[4][64];
  __shared__ float sscale;
  int bid = blockIdx.x, t = threadIdx.x;
  int i0 = (t>>4)*4, j0 = (t&15)*4;
  int rr = bid % 9;                  // spread NS blocks across CUs
  if(rr == 0){
    // ---- Newton-Schulz pseudo-inverse of kernel_2 ----
    int h = bid / 9;
    float (*Km)[PAD]=buf[0]; float (*Vm)[PAD]=buf[1]; float (*B1)[PAD]=buf[2]; float (*B2)[PAD]=buf[3];
    const float* K2 = ws + OFF_K2 + (size_t)h*4096;
    for(int i=t;i<4096;i+=256) Km[i>>6][i&63]=K2[i];
    if(t==0){
      float cm=0.f, rm=0.f;
      for(int j=0;j<BH;j++){ cm=fmaxf(cm,ws[OFF_CMAX+j]); rm=fmaxf(rm,ws[OFF_RMAX+j]); }
      sscale = 1.0f/(cm*rm);
    }
    __syncthreads();
    float scale = sscale;
    for(int i=t;i<4096;i+=256) Vm[i>>6][i&63] = scale * Km[i&63][i>>6];
    __syncthreads();
    for(int it=0; it<6; it++){
      { float c[4][4]={};
        mm_nn(c,Km,Vm,i0,j0);
        #pragma unroll
        for(int r=0;r<4;r++){ float4 o={c[r][0],c[r][1],c[r][2],c[r][3]}; st4(&B1[i0+r][j0],o); }
        __syncthreads(); }
      { float c[4][4]={};
        mm_nn_diag(c,B1,B1,i0,j0,7.0f);
        #pragma unroll
        for(int r=0;r<4;r++){ float4 o={c[r][0],c[r][1],c[r][2],c[r][3]}; st4(&B2[i0+r][j0],o); }
        __syncthreads(); }
      { float c[4][4]={};
        mm_nn_diag(c,B1,B2,i0,j0,15.0f);
        __syncthreads();
        #pragma unroll
        for(int r=0;r<4;r++){ float4 o={c[r][0],c[r][1],c[r][2],c[r][3]}; st4(&B1[i0+r][j0],o); }
        __syncthreads(); }
      { float c[4][4]={};
        mm_nn_diag(c,Vm,B1,i0,j0,13.0f);
        __syncthreads();
        #pragma unroll
        for(int r=0;r<4;r++){ float4 o={0.25f*c[r][0],0.25f*c[r][1],0.25f*c[r][2],0.25f*c[r][3]}; st4(&Vm[i0+r][j0],o); }
        __syncthreads(); }
    }
    float* W = ws + OFF_W + (size_t)h*4096;
    for(int i=t;i<4096;i+=256) W[i] = Vm[i>>6][i&63];
  } else {
    // ---- kernel_3 @ V partial: (head, 512-key chunk), register-double-buffered staging ----
    int b = (bid/9)*8 + (rr-1);
    int h = b >> 3, ch = b & 7;
    float (*Kt)[PAD]=buf[0]; float (*Vt)[PAD]=buf[1]; float (*E)[PAD]=buf[2]; float (*QLT)[PAD]=buf[3];
    const float* qlt = ws + OFF_QLT + (size_t)h*4096;
    for(int i=t;i<1024;i+=256){ int r=i>>4, c4=(i&15)*4; st4(&QLT[r][c4], ld4(qlt + r*64 + c4)); }
    const size_t kbase = ((size_t)h*SEQ + (size_t)ch*CHUNK)*DIM;
    float4 pk[4], pv[4], pk2[4], pv2[4];
    #pragma unroll
    for(int q=0;q<4;q++){
      int idx=q*256+t; int r=idx>>4, c4=(idx&15)*4;
      size_t off = kbase + (size_t)r*DIM + c4;
      pk[q]=ld4(Kg+off); pv[q]=ld4(Vg+off);
    }
    float acc[4][4]={};
    float den4[4]={};
    for(int tile=0;tile<8;tile++){
      __syncthreads();                       // prev tile's mms done -> LDS reusable
      #pragma unroll
      for(int q=0;q<4;q++){
        int idx=q*256+t; int r=idx>>4, c4=(idx&15)*4;
        float4 kv=pk[q]; kv.x*=INV_SCALE; kv.y*=INV_SCALE; kv.z*=INV_SCALE; kv.w*=INV_SCALE;
        st4(&Kt[r][c4],kv); st4(&Vt[r][c4],pv[q]);
      }
      if(tile<7){                            // prefetch next tile while computing
        #pragma unroll
        for(int q=0;q<4;q++){
          int idx=q*256+t; int r=idx>>4, c4=(idx&15)*4;
          size_t off = kbase + (size_t)((tile+1)*64+r)*DIM + c4;
          pk2[q]=ld4(Kg+off); pv2[q]=ld4(Vg+off);
        }
      }
      __syncthreads();
      float lg[4][4]={};
      mm_nn(lg, Kt, QLT, i0, j0);            // L[s'][m] = K(scaled)·QL
      float e[4][4];
      #pragma unroll
      for(int r=0;r<4;r++){
        #pragma unroll
        for(int cc=0;cc<4;cc++){ e[r][cc]=__expf(lg[r][cc]); den4[cc]+=e[r][cc]; }
      }
      #pragma unroll
      for(int r=0;r<4;r++){ float4 o={e[r][0],e[r][1],e[r][2],e[r][3]}; st4(&E[i0+r][j0],o); }
      __syncthreads();
      mm_tn(acc, E, Vt, i0, j0);             // acc[m][d] += E^T @ V  (tn-form, no transpose)
      if(tile<7){
        #pragma unroll
        for(int q=0;q<4;q++){ pk[q]=pk2[q]; pv[q]=pv2[q]; }
      }
    }
    float* num = ws + OFF_MNUM + (size_t)b*4096;
    #pragma unroll
    for(int r=0;r<4;r++){ float4 o={acc[r][0],acc[r][1],acc[r][2],acc[r][3]}; st4(num + (i0+r)*64 + j0, o); }
    #pragma unroll
    for(int cc=0;cc<4;cc++){ den4[cc]+=__shfl_xor(den4[cc],16); den4[cc]+=__shfl_xor(den4[cc],32); }
    int lane = t&63, w = t>>6;
    if(lane<16){
      #pragma unroll
      for(int cc=0;cc<4;cc++) dred[w][lane*4+cc]=den4[cc];
    }
    __syncthreads();
    if(t<64) ws[OFF_MDEN + (size_t)b*64 + t] = dred[0][t]+dred[1][t]+dred[2][t]+dred[3][t];
  }
}

// ---------------- 4. combine partials -> M, then P = W @ M ----------------
__global__ __launch_bounds__(256) void combine_kernel(float* __restrict__ ws){
  __shared__ float sW[64][PAD];
  __shared__ float sM[64][PAD];
  __shared__ float sden[64];
  int h=blockIdx.x, t=threadIdx.x;
  if(t<64){
    float s=0.f;
    for(int c=0;c<NCHUNK;c++) s += ws[OFF_MDEN + ((size_t)h*NCHUNK+c)*64 + t];
    sden[t]=1.0f/s;
  }
  for(int i=t;i<4096;i+=256) sW[i>>6][i&63] = ws[OFF_W + (size_t)h*4096 + i];
  __syncthreads();
  for(int i=t;i<1024;i+=256){
    int m=i>>4, d4=(i&15)*4;
    float sx=0.f,sy=0.f,sz=0.f,sw2=0.f;
    for(int c=0;c<NCHUNK;c++){
      float4 v = ld4(ws + OFF_MNUM + ((size_t)h*NCHUNK+c)*4096 + m*64 + d4);
      sx+=v.x; sy+=v.y; sz+=v.z; sw2+=v.w;
    }
    float iv = sden[m];
    float4 o; o.x=sx*iv; o.y=sy*iv; o.z=sz*iv; o.w=sw2*iv;
    st4(&sM[m][d4], o);
  }
  __syncthreads();
  int i0=(t>>4)*4, j0=(t&15)*4;
  float c[4][4]={};
  mm_nn(c, sW, sM, i0, j0);
  float* P = ws + OFF_P + (size_t)h*4096;
  #pragma unroll
  for(int r=0;r<4;r++){ float4 o={c[r][0],c[r][1],c[r][2],c[r][3]}; st4(P + (i0+r)*64 + j0, o); }
}

// ---------------- 5. X = rowsoftmax(Q . KL^T) @ P  (nn-form via precomputed KL^T) ----------------
__global__ __launch_bounds__(256) void final_kernel(const float* __restrict__ Qg, float* __restrict__ out, const float* __restrict__ ws){
  __shared__ float sQ[64][PAD];
  __shared__ float sB[64][PAD];   // KL^T [d][m]
  __shared__ float sP[64][PAD];
  __shared__ float sE[64][PAD];
  int bid=blockIdx.x, t=threadIdx.x;
  int h=bid>>6, s0=(bid&63)*64;
  const float* klt = ws + OFF_KLT + (size_t)h*4096;
  const float* P   = ws + OFF_P   + (size_t)h*4096;
  const float* Qb  = Qg + ((size_t)h*SEQ + (size_t)s0)*DIM;
  for(int i=t;i<1024;i+=256){
    int r=i>>4, c4=(i&15)*4;
    float4 q = ld4(Qb + (size_t)r*DIM + c4);
    q.x*=INV_SCALE; q.y*=INV_SCALE; q.z*=INV_SCALE; q.w*=INV_SCALE;
    st4(&sQ[r][c4], q);
    st4(&sB[r][c4], ld4(klt + r*64 + c4));
    st4(&sP[r][c4], ld4(P + r*64 + c4));
  }
  __syncthreads();
  int i0=(t>>4)*4, j0=(t&15)*4;
  float lg[4][4]={};
  mm_nn(lg, sQ, sB, i0, j0);
  float e[4][4], rs[4];
  #pragma unroll
  for(int r=0;r<4;r++){
    float s=0.f;
    #pragma unroll
    for(int cc=0;cc<4;cc++){ e[r][cc]=__expf(lg[r][cc]); s+=e[r][cc]; }
    rs[r]=s;
  }
  #pragma unroll
  for(int r=0;r<4;r++){
    rs[r]+=__shfl_xor(rs[r],1); rs[r]+=__shfl_xor(rs[r],2);
    rs[r]+=__shfl_xor(rs[r],4); rs[r]+=__shfl_xor(rs[r],8);
  }
  #pragma unroll
  for(int r=0;r<4;r++){ float4 o={e[r][0],e[r][1],e[r][2],e[r][3]}; st4(&sE[i0+r][j0],o); }
  __syncthreads();
  float c[4][4]={};
  mm_nn(c, sE, sP, i0, j0);
  #pragma unroll
  for(int r=0;r<4;r++){
    float iv = 1.0f/rs[r];
    float4 o; o.x=c[r][0]*iv; o.y=c[r][1]*iv; o.z=c[r][2]*iv; o.w=c[r][3]*iv;
    st4(out + ((size_t)h*SEQ + (size_t)(s0+i0+r))*DIM + j0, o);
  }
}

extern "C" void kernel_launch(void* const* d_in, const int* in_sizes, int n_in,
                              void* d_out, int out_size, void* d_ws, size_t ws_size,
                              hipStream_t stream) {
  const float* Q = (const float*)d_in[0];
  const float* K = (const float*)d_in[1];
  const float* V = (const float*)d_in[2];
  float* out = (float*)d_out;
  float* ws  = (float*)d_ws;

  pool_kernel   <<<BH*32, 256, 0, stream>>>(Q, K, ws);
  k2_kernel     <<<BH,    256, 0, stream>>>(ws);
  fused_kernel  <<<BH*9,  256, 0, stream>>>(K, V, ws);
  combine_kernel<<<BH,    256, 0, stream>>>(ws);
  final_kernel  <<<BH*64, 256, 0, stream>>>(Q, out, ws);
}

// Round 3
// 318.539 us; speedup vs baseline: 1.0218x; 1.0218x over previous
//
#include <hip/hip_runtime.h>
#include <cstdint>

#define BH 48
#define SEQ 4096
#define DIM 64
#define NCHUNK 8
#define CHUNK 512
#define PAD 68

static constexpr float INV_SCALE = 0.35355339059327379f; // 1/sqrt(sqrt(64))

typedef __attribute__((ext_vector_type(8))) short short8;
typedef __attribute__((ext_vector_type(4))) float floatx4;

#define MFMA16(a,b,c) __builtin_amdgcn_mfma_f32_16x16x32_bf16(a,b,c,0,0,0)

// workspace float offsets
#define OFF_QL   0u        // 48*4096, alive through fused (B-frags)
#define OFF_KL   196608u   // 48*4096, alive through final (A-frags)
#define OFF_PT   393216u   // 48*4096, P^T (combine -> final)
#define OFF_W    589824u   // 48*4096, NS result
#define OFF_K2   786432u   // 48*4096, kernel_2 (dead after fused -> reused as P)
#define OFF_P    OFF_K2
#define OFF_MNUM 983040u   // 48*8*4096
#define OFF_MDEN 2555904u  // 48*8*64
#define OFF_CMAX 2580480u  // 48
#define OFF_RMAX 2580528u  // 48

__device__ __forceinline__ float4 ld4(const float* p){ return *reinterpret_cast<const float4*>(p); }
__device__ __forceinline__ void st4(float* p, float4 v){ *reinterpret_cast<float4*>(p) = v; }

// fp32 -> bf16 with RNE
__device__ __forceinline__ unsigned bfr(float f){
  union{float f; unsigned u;} a; a.f=f;
  return (a.u + 0x7fffu + ((a.u>>16)&1u)) >> 16;
}
__device__ __forceinline__ int pack2(float a, float b){
  return (int)(bfr(a) | (bfr(b)<<16));
}
__device__ __forceinline__ short8 pack8(float4 a, float4 b){
  union{ short8 s; int i[4]; } u;
  u.i[0]=pack2(a.x,a.y); u.i[1]=pack2(a.z,a.w);
  u.i[2]=pack2(b.x,b.y); u.i[3]=pack2(b.z,b.w);
  return u.s;
}

// fp32 helpers for NS / combine (LDS operands, PAD=68 keeps 16B align)
__device__ __forceinline__ void mm_nn(float c[4][4], const float (*A)[PAD], const float (*B)[PAD], int i0, int j0){
  #pragma unroll 4
  for(int k=0;k<64;k+=4){
    float4 a4[4];
    #pragma unroll
    for(int r=0;r<4;r++) a4[r] = ld4(&A[i0+r][k]);
    #pragma unroll
    for(int kk=0;kk<4;kk++){
      float4 bv = ld4(&B[k+kk][j0]);
      #pragma unroll
      for(int r=0;r<4;r++){
        float a = ((const float*)&a4[r])[kk];
        c[r][0] += a*bv.x; c[r][1] += a*bv.y; c[r][2] += a*bv.z; c[r][3] += a*bv.w;
      }
    }
  }
}
__device__ __forceinline__ void mm_nn_diag(float c[4][4], const float (*A)[PAD], const float (*B)[PAD], int i0, int j0, float dg){
  #pragma unroll 4
  for(int k=0;k<64;k+=4){
    float4 a4[4];
    #pragma unroll
    for(int r=0;r<4;r++) a4[r] = ld4(&A[i0+r][k]);
    #pragma unroll
    for(int kk=0;kk<4;kk++){
      float4 bv = ld4(&B[k+kk][j0]);
      float b0=-bv.x, b1=-bv.y, b2=-bv.z, b3=-bv.w;
      int dd = k+kk-j0;
      if(dd==0) b0+=dg; else if(dd==1) b1+=dg; else if(dd==2) b2+=dg; else if(dd==3) b3+=dg;
      #pragma unroll
      for(int r=0;r<4;r++){
        float a = ((const float*)&a4[r])[kk];
        c[r][0]+=a*b0; c[r][1]+=a*b1; c[r][2]+=a*b2; c[r][3]+=a*b3;
      }
    }
  }
}

// ---------------- 1. landmark pooling ----------------
__global__ __launch_bounds__(256) void pool_kernel(const float* __restrict__ Qg, const float* __restrict__ Kg, float* __restrict__ ws){
  int bx = blockIdx.x;              // 48 heads * 2 tensors * 16 landmark-groups
  int head = bx >> 5;
  int rest = bx & 31;
  int tensor = rest >> 4;
  int l0 = (rest & 15) * 4;
  int t = threadIdx.x;
  int ll = t >> 6;
  int lane = t & 63;
  int d4 = (lane & 15) * 4;
  int rq = lane >> 4;
  const float* src = tensor ? Kg : Qg;
  float* dst = ws + (tensor ? OFF_KL : OFF_QL);
  int l = l0 + ll;
  const float* base = src + ((size_t)head*SEQ + (size_t)l*DIM)*DIM + d4;
  float sx=0.f, sy=0.f, sz=0.f, sw=0.f;
  #pragma unroll 4
  for(int r=rq; r<64; r+=4){
    float4 v = ld4(base + (size_t)r*DIM);
    sx+=v.x; sy+=v.y; sz+=v.z; sw+=v.w;
  }
  sx += __shfl_xor(sx,16); sy += __shfl_xor(sy,16); sz += __shfl_xor(sz,16); sw += __shfl_xor(sw,16);
  sx += __shfl_xor(sx,32); sy += __shfl_xor(sy,32); sz += __shfl_xor(sz,32); sw += __shfl_xor(sw,32);
  if(rq==0){
    const float sc = INV_SCALE / 64.0f;
    float4 o; o.x=sx*sc; o.y=sy*sc; o.z=sz*sc; o.w=sw*sc;
    st4(dst + ((size_t)head*64 + l)*DIM + d4, o);
  }
}

// ---------------- 2. kernel_2 softmax + per-head L1 row/col max ----------------
__global__ __launch_bounds__(256) void k2_kernel(float* __restrict__ ws){
  __shared__ float sQ[64][65];
  __shared__ float sK[64][65];
  __shared__ float sE[64][65];
  __shared__ float red[128];
  int h = blockIdx.x, t = threadIdx.x;
  const float* QL = ws + OFF_QL + (size_t)h*4096;
  const float* KL = ws + OFF_KL + (size_t)h*4096;
  for(int i=t;i<4096;i+=256){ sQ[i>>6][i&63]=QL[i]; sK[i>>6][i&63]=KL[i]; }
  __syncthreads();
  int i = t>>2, q = t&3;
  float lg[16];
  #pragma unroll
  for(int jj=0;jj<16;jj++){
    int j = q*16+jj;
    float s=0.f;
    for(int d=0;d<64;d++) s += sQ[i][d]*sK[j][d];
    lg[jj]=s;
  }
  float mx = lg[0];
  #pragma unroll
  for(int jj=1;jj<16;jj++) mx = fmaxf(mx,lg[jj]);
  mx = fmaxf(mx, __shfl_xor(mx,1));
  mx = fmaxf(mx, __shfl_xor(mx,2));
  float sum=0.f;
  #pragma unroll
  for(int jj=0;jj<16;jj++){ lg[jj]=__expf(lg[jj]-mx); sum+=lg[jj]; }
  sum += __shfl_xor(sum,1);
  sum += __shfl_xor(sum,2);
  float inv = 1.0f/sum;
  #pragma unroll
  for(int jj=0;jj<16;jj++) sE[i][q*16+jj] = lg[jj]*inv;
  __syncthreads();
  float* K2 = ws + OFF_K2 + (size_t)h*4096;
  for(int idx=t; idx<4096; idx+=256) K2[idx] = sE[idx>>6][idx&63];
  if(t<64){
    float cs=0.f, rs=0.f;
    for(int r=0;r<64;r++){ cs += sE[r][t]; rs += sE[t][r]; }
    red[t]=cs; red[64+t]=rs;
  }
  __syncthreads();
  if(t==0){
    float cm=0.f, rm=0.f;
    for(int j=0;j<64;j++){ cm=fmaxf(cm,red[j]); rm=fmaxf(rm,red[64+j]); }
    ws[OFF_CMAX+h]=cm; ws[OFF_RMAX+h]=rm;
  }
}

// ---------------- 3. fused: NS fp32 (bid%9==0) || MFMA kernel_3@V partials ----------------
__global__ __launch_bounds__(256) void fused_kernel(const float* __restrict__ Kg, const float* __restrict__ Vg, float* __restrict__ ws){
  __shared__ __align__(16) char smem[69632];
  __shared__ float dred[4][64];
  __shared__ float sscale;
  int bid = blockIdx.x, t = threadIdx.x;
  int rr = bid % 9;
  if(rr == 0){
    // ---- Newton-Schulz pseudo-inverse (fp32, needs the precision) ----
    int h = bid / 9;
    int i0 = (t>>4)*4, j0 = (t&15)*4;
    float (*Km)[PAD] = (float(*)[PAD])smem;
    float (*Vm)[PAD] = (float(*)[PAD])(smem + 17408);
    float (*B1)[PAD] = (float(*)[PAD])(smem + 34816);
    float (*B2)[PAD] = (float(*)[PAD])(smem + 52224);
    const float* K2 = ws + OFF_K2 + (size_t)h*4096;
    for(int i=t;i<4096;i+=256) Km[i>>6][i&63]=K2[i];
    if(t==0){
      float cm=0.f, rm=0.f;
      for(int j=0;j<BH;j++){ cm=fmaxf(cm,ws[OFF_CMAX+j]); rm=fmaxf(rm,ws[OFF_RMAX+j]); }
      sscale = 1.0f/(cm*rm);
    }
    __syncthreads();
    float scale = sscale;
    for(int i=t;i<4096;i+=256) Vm[i>>6][i&63] = scale * Km[i&63][i>>6];
    __syncthreads();
    for(int it=0; it<6; it++){
      { float c[4][4]={};
        mm_nn(c,Km,Vm,i0,j0);
        #pragma unroll
        for(int r=0;r<4;r++){ float4 o={c[r][0],c[r][1],c[r][2],c[r][3]}; st4(&B1[i0+r][j0],o); }
        __syncthreads(); }
      { float c[4][4]={};
        mm_nn_diag(c,B1,B1,i0,j0,7.0f);
        #pragma unroll
        for(int r=0;r<4;r++){ float4 o={c[r][0],c[r][1],c[r][2],c[r][3]}; st4(&B2[i0+r][j0],o); }
        __syncthreads(); }
      { float c[4][4]={};
        mm_nn_diag(c,B1,B2,i0,j0,15.0f);
        __syncthreads();
        #pragma unroll
        for(int r=0;r<4;r++){ float4 o={c[r][0],c[r][1],c[r][2],c[r][3]}; st4(&B1[i0+r][j0],o); }
        __syncthreads(); }
      { float c[4][4]={};
        mm_nn_diag(c,Vm,B1,i0,j0,13.0f);
        __syncthreads();
        #pragma unroll
        for(int r=0;r<4;r++){ float4 o={0.25f*c[r][0],0.25f*c[r][1],0.25f*c[r][2],0.25f*c[r][3]}; st4(&Vm[i0+r][j0],o); }
        __syncthreads(); }
    }
    float* W = ws + OFF_W + (size_t)h*4096;
    for(int i=t;i<4096;i+=256) W[i] = Vm[i>>6][i&63];
  } else {
    // ---- MFMA kernel_3 @ V partial: block = (head, 512-key chunk), 4 subtiles of 128 ----
    int b = (bid/9)*8 + (rr-1);
    int h = b >> 3, ch = b & 7;
    short (*Kb)[72]  = (short(*)[72])smem;          // K subtile, row-major bf16 [128][64+8]
    short (*Vt)[136] = (short(*)[136])(smem+18432); // V^T subtile [dv][s] bf16 [64][128+8]
    short (*Et)[136] = (short(*)[136])(smem+35840); // E^T subtile [l][s] bf16 [64][128+8]
    int lane = t & 63, w = t >> 6, quad = lane >> 4, lid = lane & 15;
    // QL B-frags, cached in regs for the whole block (B[k=d][n=l] = QL[l][d] row-major)
    short8 qlB[8];
    const float* QLh = ws + OFF_QL + (size_t)h*4096;
    #pragma unroll
    for(int nt=0; nt<4; nt++)
      #pragma unroll
      for(int kq=0; kq<2; kq++){
        const float* p = QLh + (nt*16+lid)*64 + kq*32 + quad*8;
        qlB[nt*2+kq] = pack8(ld4(p), ld4(p+4));
      }
    floatx4 Macc[16];
    #pragma unroll
    for(int i=0;i<16;i++) Macc[i] = (floatx4){0.f,0.f,0.f,0.f};
    float den4[4] = {0.f,0.f,0.f,0.f};
    const size_t base = ((size_t)h*SEQ + (size_t)ch*CHUNK)*DIM;
    for(int st=0; st<4; st++){
      __syncthreads();                       // prev subtile's MFMAs done -> LDS reusable
      // stage K (scaled, row-major) and V (transposed via shfl pair-pack)
      #pragma unroll
      for(int q=0;q<8;q++){
        int idx = q*256 + t;
        int r = idx >> 4, c4 = (idx & 15)*4;
        size_t off = base + (size_t)(st*128 + r)*64 + c4;
        float4 kv = ld4(Kg + off);
        kv.x*=INV_SCALE; kv.y*=INV_SCALE; kv.z*=INV_SCALE; kv.w*=INV_SCALE;
        *(int*)&Kb[r][c4]   = pack2(kv.x, kv.y);
        *(int*)&Kb[r][c4+2] = pack2(kv.z, kv.w);
        float4 vv = ld4(Vg + off);
        float4 ov;
        ov.x=__shfl_xor(vv.x,16); ov.y=__shfl_xor(vv.y,16);
        ov.z=__shfl_xor(vv.z,16); ov.w=__shfl_xor(vv.w,16);
        int rp = r & ~1;
        if((r & 1)==0){
          *(int*)&Vt[c4  ][rp] = pack2(vv.x, ov.x);
          *(int*)&Vt[c4+1][rp] = pack2(vv.y, ov.y);
        } else {
          *(int*)&Vt[c4+2][rp] = pack2(ov.z, vv.z);
          *(int*)&Vt[c4+3][rp] = pack2(ov.w, vv.w);
        }
      }
      __syncthreads();
      // logits L[s][l] = K·QL^T via MFMA; exp; pack E^T[l][s]
      #pragma unroll
      for(int mt=0; mt<2; mt++){
        int m0 = w*32 + mt*16;
        short8 a0 = *(const short8*)&Kb[m0+lid][quad*8];
        short8 a1 = *(const short8*)&Kb[m0+lid][32+quad*8];
        #pragma unroll
        for(int nt=0; nt<4; nt++){
          floatx4 c = (floatx4){0.f,0.f,0.f,0.f};
          c = MFMA16(a0, qlB[nt*2],   c);
          c = MFMA16(a1, qlB[nt*2+1], c);
          // lane holds col l=nt*16+lid, rows s=m0+quad*4+j
          float e0=__expf(c[0]), e1=__expf(c[1]), e2=__expf(c[2]), e3=__expf(c[3]);
          den4[nt] += e0+e1+e2+e3;
          *(int*)&Et[nt*16+lid][m0+quad*4]   = pack2(e0,e1);
          *(int*)&Et[nt*16+lid][m0+quad*4+2] = pack2(e2,e3);
        }
      }
      __syncthreads();
      // M += E^T @ V : wave w takes k-slice s in [w*32, w*32+32)
      short8 af[4], bfv[4];
      #pragma unroll
      for(int lt=0; lt<4; lt++) af[lt] = *(const short8*)&Et[lt*16+lid][w*32+quad*8];
      #pragma unroll
      for(int dt=0; dt<4; dt++) bfv[dt] = *(const short8*)&Vt[dt*16+lid][w*32+quad*8];
      #pragma unroll
      for(int lt=0; lt<4; lt++)
        #pragma unroll
        for(int dt=0; dt<4; dt++)
          Macc[lt*4+dt] = MFMA16(af[lt], bfv[dt], Macc[lt*4+dt]);
    }
    __syncthreads();
    // cross-wave reduction of M partials via LDS scratch (overlays Kb/Vt/Et)
    float (*scr)[PAD] = (float(*)[PAD])smem;   // [4*64][68]
    #pragma unroll
    for(int lt=0; lt<4; lt++)
      #pragma unroll
      for(int dt=0; dt<4; dt++)
        #pragma unroll
        for(int j=0;j<4;j++)
          scr[w*64 + lt*16 + quad*4 + j][dt*16 + lid] = Macc[lt*4+dt][j];
    #pragma unroll
    for(int nt=0; nt<4; nt++){
      den4[nt] += __shfl_xor(den4[nt], 16);
      den4[nt] += __shfl_xor(den4[nt], 32);
    }
    if(lane < 16){
      #pragma unroll
      for(int nt=0; nt<4; nt++) dred[w][nt*16+lane] = den4[nt];
    }
    __syncthreads();
    float* num = ws + OFF_MNUM + (size_t)b*4096;
    #pragma unroll
    for(int j=0;j<4;j++){
      int bi = t*16 + j*4;
      int l = bi >> 6, d0 = bi & 63;
      float4 s  = ld4(&scr[l][d0]);
      float4 s1 = ld4(&scr[64+l][d0]);
      float4 s2 = ld4(&scr[128+l][d0]);
      float4 s3 = ld4(&scr[192+l][d0]);
      s.x+=s1.x+s2.x+s3.x; s.y+=s1.y+s2.y+s3.y; s.z+=s1.z+s2.z+s3.z; s.w+=s1.w+s2.w+s3.w;
      st4(num + bi, s);
    }
    if(t < 64) ws[OFF_MDEN + (size_t)b*64 + t] = dred[0][t]+dred[1][t]+dred[2][t]+dred[3][t];
  }
}

// ---------------- 4. combine partials -> M, then P = W @ M (+ P^T) ----------------
__global__ __launch_bounds__(256) void combine_kernel(float* __restrict__ ws){
  __shared__ float sW[64][PAD];
  __shared__ float sM[64][PAD];
  __shared__ float sden[64];
  int h=blockIdx.x, t=threadIdx.x;
  if(t<64){
    float s=0.f;
    for(int c=0;c<NCHUNK;c++) s += ws[OFF_MDEN + ((size_t)h*NCHUNK+c)*64 + t];
    sden[t]=1.0f/s;
  }
  for(int i=t;i<4096;i+=256) sW[i>>6][i&63] = ws[OFF_W + (size_t)h*4096 + i];
  __syncthreads();
  for(int i=t;i<1024;i+=256){
    int m=i>>4, d4=(i&15)*4;
    float sx=0.f,sy=0.f,sz=0.f,sw2=0.f;
    for(int c=0;c<NCHUNK;c++){
      float4 v = ld4(ws + OFF_MNUM + ((size_t)h*NCHUNK+c)*4096 + m*64 + d4);
      sx+=v.x; sy+=v.y; sz+=v.z; sw2+=v.w;
    }
    float iv = sden[m];
    float4 o; o.x=sx*iv; o.y=sy*iv; o.z=sz*iv; o.w=sw2*iv;
    st4(&sM[m][d4], o);
  }
  __syncthreads();
  int i0=(t>>4)*4, j0=(t&15)*4;
  float c[4][4]={};
  mm_nn(c, sW, sM, i0, j0);
  float* P  = ws + OFF_P  + (size_t)h*4096;
  float* Pt = ws + OFF_PT + (size_t)h*4096;
  #pragma unroll
  for(int r=0;r<4;r++){
    float4 o={c[r][0],c[r][1],c[r][2],c[r][3]};
    st4(P + (i0+r)*64 + j0, o);
    #pragma unroll
    for(int cc=0;cc<4;cc++) Pt[(size_t)(j0+cc)*64 + i0+r] = c[r][cc];
  }
}

// ---------------- 5. X^T = P^T @ E^T with E = exp(KL @ Q^T), row-softmax via den regs ----------------
__global__ __launch_bounds__(256) void final_kernel(const float* __restrict__ Qg, float* __restrict__ out, const float* __restrict__ ws){
  __shared__ __align__(16) short Qb[128][72];   // Q rows (scaled) bf16
  __shared__ __align__(16) short Es[128][72];   // E[s][l] bf16
  int bid = blockIdx.x, t = threadIdx.x;
  int h = bid >> 5, s0 = (bid & 31)*128;
  int lane = t & 63, w = t >> 6, quad = lane >> 4, lid = lane & 15;
  short8 klA[8], ptA[8];
  const float* KLh = ws + OFF_KL + (size_t)h*4096;
  const float* Pth = ws + OFF_PT + (size_t)h*4096;
  #pragma unroll
  for(int mt=0; mt<4; mt++)
    #pragma unroll
    for(int kq=0; kq<2; kq++){
      const float* p  = KLh + (mt*16+lid)*64 + kq*32 + quad*8;
      klA[mt*2+kq] = pack8(ld4(p), ld4(p+4));
      const float* p2 = Pth + (mt*16+lid)*64 + kq*32 + quad*8;
      ptA[mt*2+kq] = pack8(ld4(p2), ld4(p2+4));
    }
  const float* Qgb = Qg + ((size_t)h*SEQ + (size_t)s0)*64;
  #pragma unroll
  for(int q=0;q<8;q++){
    int idx = q*256 + t;
    int r = idx >> 4, c4 = (idx & 15)*4;
    float4 v = ld4(Qgb + (size_t)r*64 + c4);
    v.x*=INV_SCALE; v.y*=INV_SCALE; v.z*=INV_SCALE; v.w*=INV_SCALE;
    *(int*)&Qb[r][c4]   = pack2(v.x,v.y);
    *(int*)&Qb[r][c4+2] = pack2(v.z,v.w);
  }
  __syncthreads();
  // Lt[l][s] = KL @ Q^T ; exp; den per s; pack E[s][l]
  float invden[2];
  #pragma unroll
  for(int st2=0; st2<2; st2++){
    int n0 = w*32 + st2*16;
    short8 b0 = *(const short8*)&Qb[n0+lid][quad*8];
    short8 b1 = *(const short8*)&Qb[n0+lid][32+quad*8];
    float den = 0.f;
    #pragma unroll
    for(int lt=0; lt<4; lt++){
      floatx4 c = (floatx4){0.f,0.f,0.f,0.f};
      c = MFMA16(klA[lt*2],   b0, c);
      c = MFMA16(klA[lt*2+1], b1, c);
      // lane holds col s=n0+lid, rows l=lt*16+quad*4+j
      float e0=__expf(c[0]), e1=__expf(c[1]), e2=__expf(c[2]), e3=__expf(c[3]);
      den += e0+e1+e2+e3;
      *(int*)&Es[n0+lid][lt*16+quad*4]   = pack2(e0,e1);
      *(int*)&Es[n0+lid][lt*16+quad*4+2] = pack2(e2,e3);
    }
    den += __shfl_xor(den,16);
    den += __shfl_xor(den,32);
    invden[st2] = 1.0f/den;
  }
  __syncthreads();
  // X^T[dv][s] = P^T @ E^T ; divide by den; store X row-major
  #pragma unroll
  for(int st2=0; st2<2; st2++){
    int n0 = w*32 + st2*16;
    short8 e0 = *(const short8*)&Es[n0+lid][quad*8];
    short8 e1 = *(const short8*)&Es[n0+lid][32+quad*8];
    float iv = invden[st2];
    #pragma unroll
    for(int dvt=0; dvt<4; dvt++){
      floatx4 c = (floatx4){0.f,0.f,0.f,0.f};
      c = MFMA16(ptA[dvt*2],   e0, c);
      c = MFMA16(ptA[dvt*2+1], e1, c);
      float4 o; o.x=c[0]*iv; o.y=c[1]*iv; o.z=c[2]*iv; o.w=c[3]*iv;
      st4(out + ((size_t)h*SEQ + (size_t)(s0 + n0 + lid))*64 + dvt*16 + quad*4, o);
    }
  }
}

extern "C" void kernel_launch(void* const* d_in, const int* in_sizes, int n_in,
                              void* d_out, int out_size, void* d_ws, size_t ws_size,
                              hipStream_t stream) {
  const float* Q = (const float*)d_in[0];
  const float* K = (const float*)d_in[1];
  const float* V = (const float*)d_in[2];
  float* out = (float*)d_out;
  float* ws  = (float*)d_ws;

  pool_kernel   <<<BH*32, 256, 0, stream>>>(Q, K, ws);
  k2_kernel     <<<BH,    256, 0, stream>>>(ws);
  fused_kernel  <<<BH*9,  256, 0, stream>>>(K, V, ws);
  combine_kernel<<<BH,    256, 0, stream>>>(ws);
  final_kernel  <<<BH*32, 256, 0, stream>>>(Q, out, ws);
}